// Round 1
// baseline (630.302 us; speedup 1.0000x reference)
//
#include <hip/hip_runtime.h>
#include <cstdint>
#include <cstddef>

#define B_   4096
#define T_   128
#define IN_  768
#define H_   256
#define BM_  64          // rows of B per workgroup

typedef __bf16 bf16_t;
typedef bf16_t bf16x8 __attribute__((ext_vector_type(8)));
typedef float  floatx4 __attribute__((ext_vector_type(4)));

#define MFMA16(a, b, c) __builtin_amdgcn_mfma_f32_16x16x32_bf16((a), (b), (c), 0, 0, 0)

__device__ __forceinline__ bf16x8 ld8(const bf16_t* p) { return *(const bf16x8*)p; }
__device__ __forceinline__ bf16x8 ld8(const float* p) {
    float4 a = *(const float4*)p;
    float4 b = *(const float4*)(p + 4);
    bf16x8 r;
    r[0] = (bf16_t)a.x; r[1] = (bf16_t)a.y; r[2] = (bf16_t)a.z; r[3] = (bf16_t)a.w;
    r[4] = (bf16_t)b.x; r[5] = (bf16_t)b.y; r[6] = (bf16_t)b.z; r[7] = (bf16_t)b.w;
    return r;
}
__device__ __forceinline__ bf16_t ld1(const bf16_t* p) { return *p; }
__device__ __forceinline__ bf16_t ld1(const float* p)  { return (bf16_t)(*p); }

// fp32 -> bf16 bulk convert (n multiple of 2048 here)
__global__ void cvt_bf16_kernel(const float* __restrict__ src, bf16_t* __restrict__ dst,
                                long long n) {
    long long i = ((long long)blockIdx.x * blockDim.x + threadIdx.x) * 8;
    if (i + 7 < n) *(bf16x8*)(dst + i) = ld8(src + i);
}

// Fused per-task 3-layer MLP. One WG = (task t, 64 rows of x).
// Wave layout: 4 waves in 2x2; each wave owns a 32x128 tile of the 64x256 output.
template <typename TW>
__global__ __launch_bounds__(256, 3)
void mtmlp_fused(const TW* __restrict__ x, const TW* __restrict__ W1,
                 const float* __restrict__ b1, const TW* __restrict__ W2,
                 const float* __restrict__ b2, const float* __restrict__ W3,
                 const float* __restrict__ b3, float* __restrict__ out) {
    const int t    = blockIdx.y;
    const int m0   = blockIdx.x * BM_;
    const int tid  = threadIdx.x;
    const int lane = tid & 63;
    const int wid  = tid >> 6;
    const int wm   = wid >> 1;     // 0..1 : rows 32*wm
    const int wn   = wid & 1;      // 0..1 : cols 128*wn
    const int lc   = lane & 15;
    const int qd   = lane >> 4;

    // LDS: h1s (32KB) holds h1 then h2, bf16 [64][256], 8-elem blocks swizzled by row&7.
    //      First 4KB aliased as xs [64][32] during layer-1 staging (blocks ^ (m>>1)&3).
    //      wt (16KB) holds transposed weight chunk [n=256][k=32] (blocks ^ (n>>1)&3);
    //      aliased as float w3s[256] in layer 3.
    __shared__ __align__(16) bf16_t h1s[BM_ * H_];
    __shared__ __align__(16) bf16_t wt[H_ * 32];
    bf16x8* h1b = (bf16x8*)h1s;
    bf16x8* xsb = (bf16x8*)h1s;
    bf16x8* wtb = (bf16x8*)wt;
    float*  w3s = (float*)wt;

    const int rowA = wm * 32 + lc;          // A-frag row (m index), +16*mi
    const int colB = wn * 128 + lc;         // B-frag col (n index), +16*nj
    const int swz  = qd ^ ((lc >> 1) & 3);  // phys block for both xs and wt frag reads
    const int swz7 = lc & 7;                // h1s swizzle key for A-frag reads

    const floatx4 fzero = {0.0f, 0.0f, 0.0f, 0.0f};
    floatx4 acc[2][8];
#pragma unroll
    for (int mi = 0; mi < 2; ++mi)
#pragma unroll
        for (int nj = 0; nj < 8; ++nj) acc[mi][nj] = fzero;

    // ---------------- layer 1: h1 = relu(x @ W1[t] + b1[t]) ----------------
    const TW* w1t = W1 + (size_t)t * IN_ * H_;
    for (int kc = 0; kc < IN_ / 32; ++kc) {
        const int k0 = kc * 32;
        __syncthreads();   // previous chunk's frag reads done before restage
        {
            // xs: 64x32, thread -> (m = tid>>2, blk = tid&3), one 16B block each
            const int m = tid >> 2, blk = tid & 3;
            xsb[m * 4 + (blk ^ ((m >> 1) & 3))] =
                ld8(x + (size_t)(m0 + m) * IN_ + k0 + blk * 8);
            // wt: [n][k] transposed stage, thread n = tid loads 32 k's (2 groups of 16)
            const int n = tid;
            const TW* pw = w1t + (size_t)k0 * H_ + n;
            const int swzn = (n >> 1) & 3;
#pragma unroll
            for (int g = 0; g < 2; ++g) {
                bf16_t tmp[16];
#pragma unroll
                for (int j = 0; j < 16; ++j) tmp[j] = ld1(pw + (g * 16 + j) * H_);
#pragma unroll
                for (int h = 0; h < 2; ++h) {
                    bf16x8 v;
#pragma unroll
                    for (int e = 0; e < 8; ++e) v[e] = tmp[h * 8 + e];
                    wtb[n * 4 + ((g * 2 + h) ^ swzn)] = v;
                }
            }
        }
        __syncthreads();
        const bf16x8 a0 = xsb[rowA * 4 + swz];
        const bf16x8 a1 = xsb[(rowA + 16) * 4 + swz];
#pragma unroll
        for (int nj = 0; nj < 8; ++nj) {
            const bf16x8 b = wtb[(colB + nj * 16) * 4 + swz];
            acc[0][nj] = MFMA16(a0, b, acc[0][nj]);
            acc[1][nj] = MFMA16(a1, b, acc[1][nj]);
        }
    }

    // epilogue 1: bias + relu -> h1s (bf16, swizzled)
    {
        float bias[8];
#pragma unroll
        for (int nj = 0; nj < 8; ++nj) bias[nj] = b1[t * H_ + wn * 128 + nj * 16 + lc];
        __syncthreads();   // all xs/wt reads finished before overwriting h1s region
#pragma unroll
        for (int mi = 0; mi < 2; ++mi)
#pragma unroll
            for (int nj = 0; nj < 8; ++nj)
#pragma unroll
                for (int r = 0; r < 4; ++r) {
                    float v = acc[mi][nj][r] + bias[nj];
                    v = v > 0.0f ? v : 0.0f;
                    const int row = wm * 32 + mi * 16 + qd * 4 + r;
                    const int col = wn * 128 + nj * 16 + lc;
                    h1s[row * H_ + (((col >> 3) ^ (row & 7)) << 3) + (col & 7)] =
                        (bf16_t)v;
                }
    }

#pragma unroll
    for (int mi = 0; mi < 2; ++mi)
#pragma unroll
        for (int nj = 0; nj < 8; ++nj) acc[mi][nj] = fzero;

    // ---------------- layer 2: h2 = relu(h1 @ W2[t] + b2[t]) ----------------
    const TW* w2t = W2 + (size_t)t * H_ * H_;
    for (int kc = 0; kc < H_ / 32; ++kc) {
        const int k0 = kc * 32;
        __syncthreads();
        {
            const int n = tid;
            const TW* pw = w2t + (size_t)k0 * H_ + n;
            const int swzn = (n >> 1) & 3;
#pragma unroll
            for (int g = 0; g < 2; ++g) {
                bf16_t tmp[16];
#pragma unroll
                for (int j = 0; j < 16; ++j) tmp[j] = ld1(pw + (g * 16 + j) * H_);
#pragma unroll
                for (int h = 0; h < 2; ++h) {
                    bf16x8 v;
#pragma unroll
                    for (int e = 0; e < 8; ++e) v[e] = tmp[h * 8 + e];
                    wtb[n * 4 + ((g * 2 + h) ^ swzn)] = v;
                }
            }
        }
        __syncthreads();
        const bf16x8 a0 = h1b[rowA * 32 + ((kc * 4 + qd) ^ swz7)];
        const bf16x8 a1 = h1b[(rowA + 16) * 32 + ((kc * 4 + qd) ^ swz7)];
#pragma unroll
        for (int nj = 0; nj < 8; ++nj) {
            const bf16x8 b = wtb[(colB + nj * 16) * 4 + swz];
            acc[0][nj] = MFMA16(a0, b, acc[0][nj]);
            acc[1][nj] = MFMA16(a1, b, acc[1][nj]);
        }
    }

    // epilogue 2: bias + relu -> h2 (reuse h1s buffer), stage W3 -> w3s
    {
        float bias[8];
#pragma unroll
        for (int nj = 0; nj < 8; ++nj) bias[nj] = b2[t * H_ + wn * 128 + nj * 16 + lc];
        __syncthreads();   // all h1s/wt reads finished
#pragma unroll
        for (int mi = 0; mi < 2; ++mi)
#pragma unroll
            for (int nj = 0; nj < 8; ++nj)
#pragma unroll
                for (int r = 0; r < 4; ++r) {
                    float v = acc[mi][nj][r] + bias[nj];
                    v = v > 0.0f ? v : 0.0f;
                    const int row = wm * 32 + mi * 16 + qd * 4 + r;
                    const int col = wn * 128 + nj * 16 + lc;
                    h1s[row * H_ + (((col >> 3) ^ (row & 7)) << 3) + (col & 7)] =
                        (bf16_t)v;
                }
        w3s[tid] = W3[t * H_ + tid];   // 256 threads == 256 floats
    }
    __syncthreads();

    // ---------------- layer 3: out[b,t] = h2[b,:] . W3[t,:] + b3[t] ----------------
    {
        const int row = tid >> 2, seg = tid & 3;   // 4 threads per row, 64 cols each
        float sum = 0.0f;
#pragma unroll
        for (int b8 = 0; b8 < 8; ++b8) {
            const int blk = seg * 8 + b8;
            const bf16x8 v = h1b[row * 32 + (blk ^ (row & 7))];
#pragma unroll
            for (int e = 0; e < 8; ++e) sum += (float)v[e] * w3s[blk * 8 + e];
        }
        sum += __shfl_xor(sum, 1);
        sum += __shfl_xor(sum, 2);
        if (seg == 0) out[(size_t)(m0 + row) * T_ + t] = sum + b3[t];
    }
}

extern "C" void kernel_launch(void* const* d_in, const int* in_sizes, int n_in,
                              void* d_out, int out_size, void* d_ws, size_t ws_size,
                              hipStream_t stream) {
    const float* x  = (const float*)d_in[0];
    const float* W1 = (const float*)d_in[1];
    const float* b1 = (const float*)d_in[2];
    const float* W2 = (const float*)d_in[3];
    const float* b2 = (const float*)d_in[4];
    const float* W3 = (const float*)d_in[5];
    const float* b3 = (const float*)d_in[6];
    float* out = (float*)d_out;

    const size_t nx  = (size_t)B_ * IN_;        // 3,145,728
    const size_t nw1 = (size_t)T_ * IN_ * H_;   // 25,165,824
    const size_t nw2 = (size_t)T_ * H_ * H_;    // 8,388,608
    const size_t need = (nx + nw1 + nw2) * sizeof(bf16_t);   // ~73.4 MB

    dim3 grid(B_ / BM_, T_);   // (64, 128); same-t blocks adjacent -> W[t] stays hot in L2

    if (d_ws != nullptr && ws_size >= need) {
        // Pre-convert x/W1/W2 to bf16 in workspace: halves refetch bytes, drops
        // per-chunk cvts from the hot loop.
        bf16_t* xb  = (bf16_t*)d_ws;
        bf16_t* w1b = xb + nx;
        bf16_t* w2b = w1b + nw1;
        cvt_bf16_kernel<<<dim3((unsigned)(nx / 2048)), 256, 0, stream>>>(x, xb, (long long)nx);
        cvt_bf16_kernel<<<dim3((unsigned)(nw1 / 2048)), 256, 0, stream>>>(W1, w1b, (long long)nw1);
        cvt_bf16_kernel<<<dim3((unsigned)(nw2 / 2048)), 256, 0, stream>>>(W2, w2b, (long long)nw2);
        mtmlp_fused<bf16_t><<<grid, 256, 0, stream>>>(xb, w1b, b1, w2b, b2, W3, b3, out);
    } else {
        // Fallback: convert fp32->bf16 inline while staging.
        mtmlp_fused<float><<<grid, 256, 0, stream>>>(x, W1, b1, W2, b2, W3, b3, out);
    }
}

// Round 2
// 500.589 us; speedup vs baseline: 1.2591x; 1.2591x over previous
//
#include <hip/hip_runtime.h>
#include <cstdint>
#include <cstddef>

#define B_   4096
#define T_   128
#define IN_  768
#define H_   256
#define BM_  128          // batch rows per workgroup
#define KC1  (IN_ / 32)   // 24 k-chunks, layer 1
#define KC2  (H_ / 32)    // 8  k-chunks, layer 2

typedef __bf16 bf16_t;
typedef bf16_t bf16x8  __attribute__((ext_vector_type(8)));
typedef bf16_t bf16x4  __attribute__((ext_vector_type(4)));
typedef float  floatx16 __attribute__((ext_vector_type(16)));

#define MFMA32(a, b, c) __builtin_amdgcn_mfma_f32_32x32x16_bf16((a), (b), (c), 0, 0, 0)

// async global->LDS, 16B per lane (wave-uniform base + lane*16 pattern)
__device__ __forceinline__ void gl_lds16(const bf16_t* g, bf16_t* l) {
    __builtin_amdgcn_global_load_lds(
        (const __attribute__((address_space(1))) void*)g,
        (__attribute__((address_space(3))) void*)l, 16, 0, 0);
}

// ---------- transform: W [t][K][H] fp32 -> A-frag tiles [t][kc][kq=4][h=256][8k] bf16 ----------
__global__ void tile_w_kernel(const float* __restrict__ src, bf16_t* __restrict__ dst,
                              int K, int KC, long long total8) {
    long long o = (long long)blockIdx.x * blockDim.x + threadIdx.x;
    if (o >= total8) return;
    int h  = (int)(o & (H_ - 1));
    long long q = o >> 8;
    int kq = (int)(q & 3);
    int q2 = (int)(q >> 2);
    int kc = q2 % KC;
    int t  = q2 / KC;
    const float* s = src + ((long long)t * K + kc * 32 + kq * 8) * H_ + h;
    bf16x8 v;
#pragma unroll
    for (int e = 0; e < 8; ++e) v[e] = (bf16_t)s[(long long)e * H_];   // coalesced across lanes
    *(bf16x8*)(dst + o * 8) = v;
}

// ---------- transform: x [B][IN] fp32 -> B-frag tiles [mblk][kc][kq=4][m=128][8k] bf16 ----------
__global__ void tile_x_kernel(const float* __restrict__ src, bf16_t* __restrict__ dst,
                              long long total8) {
    long long o = (long long)blockIdx.x * blockDim.x + threadIdx.x;
    if (o >= total8) return;
    int m = (int)(o & (BM_ - 1));
    long long q = o >> 7;
    int kq = (int)(q & 3);
    int q2 = (int)(q >> 2);
    int kc   = q2 % KC1;
    int mblk = q2 / KC1;
    const float* s = src + ((long long)mblk * BM_ + m) * IN_ + kc * 32 + kq * 8;
    float4 a = *(const float4*)s;
    float4 b = *(const float4*)(s + 4);
    bf16x8 v;
    v[0] = (bf16_t)a.x; v[1] = (bf16_t)a.y; v[2] = (bf16_t)a.z; v[3] = (bf16_t)a.w;
    v[4] = (bf16_t)b.x; v[5] = (bf16_t)b.y; v[6] = (bf16_t)b.z; v[7] = (bf16_t)b.w;
    *(bf16x8*)(dst + o * 8) = v;
}

// ---------- fused per-task MLP: computes h^T = W^T x^T so the MFMA C/D layout
// (col = batch row m) packs into b64 stores of 4 contiguous h, matching the
// B-frag read pattern (8 contiguous h per fixed m) of the next layer. ----------
__global__ __launch_bounds__(256, 2)
void mtmlp_fused2(const bf16_t* __restrict__ xt, const bf16_t* __restrict__ w1t,
                  const float* __restrict__ b1, const bf16_t* __restrict__ w2t,
                  const float* __restrict__ b2, const float* __restrict__ W3,
                  const float* __restrict__ b3, float* __restrict__ out) {
    const int mblk = blockIdx.x;
    const int t    = blockIdx.y;
    const int m0   = mblk * BM_;
    const int tid  = threadIdx.x;
    const int lane = tid & 63;
    const int wid  = tid >> 6;
    const int wm   = wid >> 1;      // h-half: wm*128
    const int wn   = wid & 1;       // m-half: wn*64
    const int ln31 = lane & 31;
    const int hi   = lane >> 5;

    // LDS: hbuf 64KB ([m=128][h=256] bf16, 8-el blocks XOR-swizzled by m&7);
    //      first 8KB aliased as xs ([kq=4][m=128][8]) during layer 1.
    //      wt 16KB ([kq=4][row=256][8]) = A-fragment image of one weight chunk.
    __shared__ __align__(16) bf16_t hbuf[BM_ * H_];
    __shared__ __align__(16) bf16_t wt[4 * H_ * 8];
    bf16_t* xs = hbuf;
    float*  w3s = (float*)wt;

    floatx16 acc[4][2];
#pragma unroll
    for (int i = 0; i < 4; ++i)
#pragma unroll
        for (int j = 0; j < 2; ++j)
#pragma unroll
            for (int e = 0; e < 16; ++e) acc[i][j][e] = 0.0f;

    // ---------------- layer 1: h1^T = W1^T · x^T ----------------
    const bf16_t* w1base = w1t + (size_t)(t * KC1) * 8192;       // 16KB tiles
    const bf16_t* xbase  = xt + (size_t)(mblk * KC1) * 4096;     // 8KB tiles
    for (int kc = 0; kc < KC1; ++kc) {
        __syncthreads();
        {   // stage: pure contiguous async copies, ws layout == LDS image
            const bf16_t* wsrc = w1base + kc * 8192;
            const bf16_t* xsrc = xbase + kc * 4096;
            const int off = wid * 2048 + lane * 8;
#pragma unroll
            for (int r = 0; r < 4; ++r) gl_lds16(wsrc + off + r * 512, wt + off + r * 512);
            const int xoff = wid * 1024 + lane * 8;
#pragma unroll
            for (int r = 0; r < 2; ++r) gl_lds16(xsrc + xoff + r * 512, xs + xoff + r * 512);
        }
        __syncthreads();
#pragma unroll
        for (int s = 0; s < 2; ++s) {
            const int kq = s * 2 + hi;
            bf16x8 A[4], Bf[2];
#pragma unroll
            for (int i = 0; i < 4; ++i)
                A[i] = *(const bf16x8*)(wt + (size_t)(kq * H_ + wm * 128 + i * 32 + ln31) * 8);
#pragma unroll
            for (int j = 0; j < 2; ++j)
                Bf[j] = *(const bf16x8*)(xs + (size_t)(kq * BM_ + wn * 64 + j * 32 + ln31) * 8);
#pragma unroll
            for (int i = 0; i < 4; ++i)
#pragma unroll
                for (int j = 0; j < 2; ++j) acc[i][j] = MFMA32(A[i], Bf[j], acc[i][j]);
        }
    }

    // epilogue 1: bias + relu, pack reg-quads (4 contiguous h) -> b64 stores
    __syncthreads();
#pragma unroll
    for (int i = 0; i < 4; ++i) {
        const int hb = wm * 128 + i * 32;
#pragma unroll
        for (int g = 0; g < 4; ++g) {
            const int h0 = hb + g * 8 + 4 * hi;
            float4 bias = *(const float4*)(b1 + t * H_ + h0);
            const int blk = h0 >> 3;
#pragma unroll
            for (int j = 0; j < 2; ++j) {
                const int m = wn * 64 + j * 32 + ln31;
                bf16x4 o;
                o[0] = (bf16_t)fmaxf(acc[i][j][4 * g + 0] + bias.x, 0.0f);
                o[1] = (bf16_t)fmaxf(acc[i][j][4 * g + 1] + bias.y, 0.0f);
                o[2] = (bf16_t)fmaxf(acc[i][j][4 * g + 2] + bias.z, 0.0f);
                o[3] = (bf16_t)fmaxf(acc[i][j][4 * g + 3] + bias.w, 0.0f);
                *(bf16x4*)(hbuf + (size_t)m * H_ + (blk ^ (m & 7)) * 8 + 4 * hi) = o;
            }
        }
    }

#pragma unroll
    for (int i = 0; i < 4; ++i)
#pragma unroll
        for (int j = 0; j < 2; ++j)
#pragma unroll
            for (int e = 0; e < 16; ++e) acc[i][j][e] = 0.0f;

    // ---------------- layer 2: h2^T = W2^T · h1^T ----------------
    const bf16_t* w2base = w2t + (size_t)(t * KC2) * 8192;
    for (int kc = 0; kc < KC2; ++kc) {
        __syncthreads();
        {
            const bf16_t* wsrc = w2base + kc * 8192;
            const int off = wid * 2048 + lane * 8;
#pragma unroll
            for (int r = 0; r < 4; ++r) gl_lds16(wsrc + off + r * 512, wt + off + r * 512);
        }
        __syncthreads();
#pragma unroll
        for (int s = 0; s < 2; ++s) {
            const int kq = s * 2 + hi;
            bf16x8 A[4], Bf[2];
#pragma unroll
            for (int i = 0; i < 4; ++i)
                A[i] = *(const bf16x8*)(wt + (size_t)(kq * H_ + wm * 128 + i * 32 + ln31) * 8);
            const int blk = kc * 4 + kq;
#pragma unroll
            for (int j = 0; j < 2; ++j) {
                const int m = wn * 64 + j * 32 + ln31;
                Bf[j] = *(const bf16x8*)(hbuf + (size_t)m * H_ + (blk ^ (m & 7)) * 8);
            }
#pragma unroll
            for (int i = 0; i < 4; ++i)
#pragma unroll
                for (int j = 0; j < 2; ++j) acc[i][j] = MFMA32(A[i], Bf[j], acc[i][j]);
        }
    }

    // epilogue 2: bias + relu -> h2 overwrites hbuf (same layout); stage W3
    __syncthreads();
    w3s[tid] = W3[t * H_ + tid];
#pragma unroll
    for (int i = 0; i < 4; ++i) {
        const int hb = wm * 128 + i * 32;
#pragma unroll
        for (int g = 0; g < 4; ++g) {
            const int h0 = hb + g * 8 + 4 * hi;
            float4 bias = *(const float4*)(b2 + t * H_ + h0);
            const int blk = h0 >> 3;
#pragma unroll
            for (int j = 0; j < 2; ++j) {
                const int m = wn * 64 + j * 32 + ln31;
                bf16x4 o;
                o[0] = (bf16_t)fmaxf(acc[i][j][4 * g + 0] + bias.x, 0.0f);
                o[1] = (bf16_t)fmaxf(acc[i][j][4 * g + 1] + bias.y, 0.0f);
                o[2] = (bf16_t)fmaxf(acc[i][j][4 * g + 2] + bias.z, 0.0f);
                o[3] = (bf16_t)fmaxf(acc[i][j][4 * g + 3] + bias.w, 0.0f);
                *(bf16x4*)(hbuf + (size_t)m * H_ + (blk ^ (m & 7)) * 8 + 4 * hi) = o;
            }
        }
    }
    __syncthreads();

    // ---------------- layer 3: out[m,t] = h2[m,:]·W3[t,:] + b3[t] ----------------
    {
        const int m = tid >> 1, seg = tid & 1;   // 2 threads per row, 128 h each
        float sum = 0.0f;
#pragma unroll
        for (int b = 0; b < 16; ++b) {
            const int blk = seg * 16 + b;
            const bf16x8 v = *(const bf16x8*)(hbuf + (size_t)m * H_ + (blk ^ (m & 7)) * 8);
            const float* w = w3s + blk * 8;
#pragma unroll
            for (int e = 0; e < 8; ++e) sum += (float)v[e] * w[e];
        }
        sum += __shfl_xor(sum, 1);
        if (seg == 0) out[(size_t)(m0 + m) * T_ + t] = sum + b3[t];
    }
}

extern "C" void kernel_launch(void* const* d_in, const int* in_sizes, int n_in,
                              void* d_out, int out_size, void* d_ws, size_t ws_size,
                              hipStream_t stream) {
    const float* x  = (const float*)d_in[0];
    const float* W1 = (const float*)d_in[1];
    const float* b1 = (const float*)d_in[2];
    const float* W2 = (const float*)d_in[3];
    const float* b2 = (const float*)d_in[4];
    const float* W3 = (const float*)d_in[5];
    const float* b3 = (const float*)d_in[6];
    float* out = (float*)d_out;

    const size_t nx  = (size_t)B_ * IN_;        // 3,145,728
    const size_t nw1 = (size_t)T_ * IN_ * H_;   // 25,165,824
    const size_t nw2 = (size_t)T_ * H_ * H_;    // 8,388,608

    bf16_t* xt  = (bf16_t*)d_ws;
    bf16_t* w1t = xt + nx;
    bf16_t* w2t = w1t + nw1;

    // pre-tile into MFMA fragment images (bf16)
    tile_x_kernel<<<dim3((unsigned)(nx / 8 / 256)), 256, 0, stream>>>(x, xt, (long long)(nx / 8));
    tile_w_kernel<<<dim3((unsigned)(nw1 / 8 / 256)), 256, 0, stream>>>(W1, w1t, IN_, KC1, (long long)(nw1 / 8));
    tile_w_kernel<<<dim3((unsigned)(nw2 / 8 / 256)), 256, 0, stream>>>(W2, w2t, H_, KC2, (long long)(nw2 / 8));

    dim3 grid(B_ / BM_, T_);   // (32, 128): same-t blocks adjacent for L2 reuse of W[t]
    mtmlp_fused2<<<grid, 256, 0, stream>>>(xt, w1t, b1, w2t, b2, W3, b3, out);
}

// Round 3
// 474.443 us; speedup vs baseline: 1.3285x; 1.0551x over previous
//
#include <hip/hip_runtime.h>
#include <cstdint>
#include <cstddef>

#define B_   4096
#define T_   128
#define IN_  768
#define H_   256
#define BM_  256          // batch rows per workgroup (two 128-row x tiles)
#define KC1  (IN_ / 32)   // 24 k-chunks, layer 1
#define KC2  (H_ / 32)    // 8  k-chunks, layer 2

typedef __bf16 bf16_t;
typedef bf16_t bf16x8 __attribute__((ext_vector_type(8)));
typedef bf16_t bf16x4 __attribute__((ext_vector_type(4)));
typedef float  floatx16 __attribute__((ext_vector_type(16)));

#define MFMA32(a, b, c) __builtin_amdgcn_mfma_f32_32x32x16_bf16((a), (b), (c), 0, 0, 0)

__device__ __forceinline__ void gl_lds16(const bf16_t* g, bf16_t* l) {
    __builtin_amdgcn_global_load_lds(
        (const __attribute__((address_space(1))) void*)g,
        (__attribute__((address_space(3))) void*)l, 16, 0, 0);
}

// ---------- W [t][K][H] fp32 -> A-frag tiles [t][kc][kq=4][h=256][8k] bf16 ----------
// One block per (t,kc) 32k x 256h tile. float4 reads, 64B-contiguous writes per thread.
__global__ __launch_bounds__(256)
void tile_w2(const float* __restrict__ src, bf16_t* __restrict__ dst, int K, int KC) {
    const int t  = blockIdx.x / KC;
    const int kc = blockIdx.x - t * KC;
    const int kq = threadIdx.x >> 6;           // 0..3
    const int h4 = (threadIdx.x & 63) * 4;     // 0..252
    const float* s = src + ((size_t)t * K + kc * 32 + kq * 8) * H_ + h4;
    float r[8][4];
#pragma unroll
    for (int e = 0; e < 8; ++e) {
        float4 v = *(const float4*)(s + (size_t)e * H_);
        r[e][0] = v.x; r[e][1] = v.y; r[e][2] = v.z; r[e][3] = v.w;
    }
    bf16_t* d = dst + (((size_t)(t * KC + kc) * 4 + kq) * H_ + h4) * 8;
#pragma unroll
    for (int c = 0; c < 4; ++c) {
        bf16x8 v;
#pragma unroll
        for (int e = 0; e < 8; ++e) v[e] = (bf16_t)r[e][c];
        *(bf16x8*)(d + c * 8) = v;
    }
}

// ---------- x [B][IN] fp32 -> B-frag tiles [mblk][kc][kq=4][m=128][8k] bf16 ----------
__global__ void tile_x_kernel(const float* __restrict__ src, bf16_t* __restrict__ dst,
                              long long total8) {
    long long o = (long long)blockIdx.x * blockDim.x + threadIdx.x;
    if (o >= total8) return;
    int m = (int)(o & 127);
    long long q = o >> 7;
    int kq = (int)(q & 3);
    int q2 = (int)(q >> 2);
    int kc   = q2 % KC1;
    int mblk = q2 / KC1;
    const float* s = src + ((long long)mblk * 128 + m) * IN_ + kc * 32 + kq * 8;
    float4 a = *(const float4*)s;
    float4 b = *(const float4*)(s + 4);
    bf16x8 v;
    v[0] = (bf16_t)a.x; v[1] = (bf16_t)a.y; v[2] = (bf16_t)a.z; v[3] = (bf16_t)a.w;
    v[4] = (bf16_t)b.x; v[5] = (bf16_t)b.y; v[6] = (bf16_t)b.z; v[7] = (bf16_t)b.w;
    *(bf16x8*)(dst + o * 8) = v;
}

// ---------- fused per-task MLP, mega-WG: 512 threads, 256 batch rows, 1 WG/CU.
// Layer1 K-loop: ring-2 double buffer (wt 16KB + xs 16KB per chunk) living inside
// hbuf (dead until epilogue-1); ONE barrier per chunk — the vmcnt drain waits on
// loads issued a full chunk earlier, so it's ~free.
// hbuf layout [blk=h/8][m=256][8h] bf16: epilogue b64 stores, layer2 B-frag b128
// reads, and layer3 reads are all lane-contiguous (no bank conflicts). ----------
__global__ __launch_bounds__(512, 2)
void mtmlp_fused3(const bf16_t* __restrict__ xt, const bf16_t* __restrict__ w1t,
                  const float* __restrict__ b1, const bf16_t* __restrict__ w2t,
                  const float* __restrict__ b2, const float* __restrict__ W3,
                  const float* __restrict__ b3, float* __restrict__ out) {
    // XCD-locality swizzle: hardware maps consecutive workgroup ids round-robin
    // across 8 XCDs. Decode so XCD k owns tasks [16k,16k+16): W1[t]/W2[t] stay
    // L2-resident per XCD; the 2 co-running t's share x through L2 too.
    const int L    = blockIdx.x;          // 0..2047
    const int xcd  = L & 7;
    const int slot = L >> 3;              // 0..255
    const int t    = xcd * 16 + (slot >> 4);
    const int mblk = slot & 15;
    const int m0   = mblk * BM_;
    const int mb0  = mblk * 2;            // 128-row tile index

    const int tid  = threadIdx.x;
    const int lane = tid & 63;
    const int wid  = tid >> 6;            // 0..7
    const int wm   = wid >> 2;            // 0..1 : h half (128)
    const int wn   = wid & 3;             // 0..3 : m quarter (64)
    const int ln31 = lane & 31;
    const int hi   = lane >> 5;

    __shared__ __align__(16) bf16_t hbuf[BM_ * H_];    // 128 KB
    __shared__ __align__(16) bf16_t wt2[4 * H_ * 8];   // 16 KB (layer-2 W chunk; w3s alias)
    float* w3s = (float*)wt2;

    floatx16 acc[4][2];
#pragma unroll
    for (int i = 0; i < 4; ++i)
#pragma unroll
        for (int j = 0; j < 2; ++j)
#pragma unroll
            for (int e = 0; e < 16; ++e) acc[i][j][e] = 0.0f;

    // ---------------- layer 1: h1^T = W1^T · x^T ----------------
    const bf16_t* w1base = w1t + (size_t)t * KC1 * 8192;
    const bf16_t* x0base = xt + (size_t)mb0 * KC1 * 4096;
    const bf16_t* x1base = xt + (size_t)(mb0 + 1) * KC1 * 4096;

    auto stage1 = [&](bf16_t* buf, int kc) {
        const bf16_t* ws = w1base + (size_t)kc * 8192;
        gl_lds16(ws + tid * 8,        buf + tid * 8);
        gl_lds16(ws + 4096 + tid * 8, buf + 4096 + tid * 8);
        gl_lds16(x0base + (size_t)kc * 4096 + tid * 8, buf + 8192 + tid * 8);
        gl_lds16(x1base + (size_t)kc * 4096 + tid * 8, buf + 12288 + tid * 8);
    };
    auto comp1 = [&](const bf16_t* buf) {
#pragma unroll
        for (int s = 0; s < 2; ++s) {
            const int kq = s * 2 + hi;
            bf16x8 A[4], Bf[2];
#pragma unroll
            for (int i = 0; i < 4; ++i)
                A[i] = *(const bf16x8*)(buf + (size_t)(kq * H_ + wm * 128 + i * 32 + ln31) * 8);
#pragma unroll
            for (int j = 0; j < 2; ++j) {
                const int mm = wn * 64 + j * 32 + ln31;
                Bf[j] = *(const bf16x8*)(buf + 8192 + (mm >> 7) * 4096 +
                                         (size_t)(kq * 128 + (mm & 127)) * 8);
            }
#pragma unroll
            for (int i = 0; i < 4; ++i)
#pragma unroll
                for (int j = 0; j < 2; ++j) acc[i][j] = MFMA32(A[i], Bf[j], acc[i][j]);
        }
    };

    bf16_t* buf0 = hbuf;            // ring inside hbuf (free until epilogue-1)
    bf16_t* buf1 = hbuf + 16384;
    stage1(buf0, 0);
    for (int kc = 0; kc < KC1; kc += 2) {
        __syncthreads();                       // buf0(kc) ready; buf1 readers done
        stage1(buf1, kc + 1);                  // kc+1 <= 23 always
        comp1(buf0);
        __syncthreads();                       // buf1 ready; buf0 readers done
        if (kc + 2 < KC1) stage1(buf0, kc + 2);
        comp1(buf1);
    }
    __syncthreads();   // ring reads done before epilogue overwrites hbuf

    // epilogue 1: bias + relu -> hbuf [blk][m][8]
#pragma unroll
    for (int i = 0; i < 4; ++i) {
#pragma unroll
        for (int g = 0; g < 4; ++g) {
            const int h0 = wm * 128 + i * 32 + g * 8 + 4 * hi;
            float4 bias = *(const float4*)(b1 + t * H_ + h0);
            const int blk = h0 >> 3;
#pragma unroll
            for (int j = 0; j < 2; ++j) {
                const int mm = wn * 64 + j * 32 + ln31;
                bf16x4 o;
                o[0] = (bf16_t)fmaxf(acc[i][j][4 * g + 0] + bias.x, 0.0f);
                o[1] = (bf16_t)fmaxf(acc[i][j][4 * g + 1] + bias.y, 0.0f);
                o[2] = (bf16_t)fmaxf(acc[i][j][4 * g + 2] + bias.z, 0.0f);
                o[3] = (bf16_t)fmaxf(acc[i][j][4 * g + 3] + bias.w, 0.0f);
                *(bf16x4*)(hbuf + (size_t)(blk * BM_ + mm) * 8 + 4 * hi) = o;
            }
        }
    }

#pragma unroll
    for (int i = 0; i < 4; ++i)
#pragma unroll
        for (int j = 0; j < 2; ++j)
#pragma unroll
            for (int e = 0; e < 16; ++e) acc[i][j][e] = 0.0f;

    // ---------------- layer 2: h2^T = W2^T · h1^T ----------------
    const bf16_t* w2base = w2t + (size_t)t * KC2 * 8192;
    for (int kc = 0; kc < KC2; ++kc) {
        __syncthreads();                       // wt2 readers from prev chunk done
        const bf16_t* ws = w2base + (size_t)kc * 8192;
        gl_lds16(ws + tid * 8,        wt2 + tid * 8);
        gl_lds16(ws + 4096 + tid * 8, wt2 + 4096 + tid * 8);
        __syncthreads();                       // wt2 ready (also orders ep-1 writes, kc=0)
#pragma unroll
        for (int s = 0; s < 2; ++s) {
            const int kq = s * 2 + hi;
            bf16x8 A[4], Bf[2];
#pragma unroll
            for (int i = 0; i < 4; ++i)
                A[i] = *(const bf16x8*)(wt2 + (size_t)(kq * H_ + wm * 128 + i * 32 + ln31) * 8);
            const int blk = kc * 4 + kq;
#pragma unroll
            for (int j = 0; j < 2; ++j) {
                const int mm = wn * 64 + j * 32 + ln31;
                Bf[j] = *(const bf16x8*)(hbuf + (size_t)(blk * BM_ + mm) * 8);
            }
#pragma unroll
            for (int i = 0; i < 4; ++i)
#pragma unroll
                for (int j = 0; j < 2; ++j) acc[i][j] = MFMA32(A[i], Bf[j], acc[i][j]);
        }
    }

    // epilogue 2: bias + relu -> h2 (hbuf, same layout); stage W3 into w3s
    __syncthreads();   // all wt2/hbuf reads done
    if (tid < H_) w3s[tid] = W3[t * H_ + tid];
#pragma unroll
    for (int i = 0; i < 4; ++i) {
#pragma unroll
        for (int g = 0; g < 4; ++g) {
            const int h0 = wm * 128 + i * 32 + g * 8 + 4 * hi;
            float4 bias = *(const float4*)(b2 + t * H_ + h0);
            const int blk = h0 >> 3;
#pragma unroll
            for (int j = 0; j < 2; ++j) {
                const int mm = wn * 64 + j * 32 + ln31;
                bf16x4 o;
                o[0] = (bf16_t)fmaxf(acc[i][j][4 * g + 0] + bias.x, 0.0f);
                o[1] = (bf16_t)fmaxf(acc[i][j][4 * g + 1] + bias.y, 0.0f);
                o[2] = (bf16_t)fmaxf(acc[i][j][4 * g + 2] + bias.z, 0.0f);
                o[3] = (bf16_t)fmaxf(acc[i][j][4 * g + 3] + bias.w, 0.0f);
                *(bf16x4*)(hbuf + (size_t)(blk * BM_ + mm) * 8 + 4 * hi) = o;
            }
        }
    }
    __syncthreads();

    // ---------------- layer 3: out[m,t] = h2[m,:]·W3[t,:] + b3[t] ----------------
    {
        const int m = tid >> 1, seg = tid & 1;   // 2 threads/row, 128 h each
        float sum = 0.0f;
#pragma unroll
        for (int b = 0; b < 16; ++b) {
            const int blk = seg * 16 + b;
            const bf16x8 v = *(const bf16x8*)(hbuf + (size_t)(blk * BM_ + m) * 8);
            const float* w = w3s + blk * 8;
#pragma unroll
            for (int e = 0; e < 8; ++e) sum += (float)v[e] * w[e];
        }
        sum += __shfl_xor(sum, 1);
        if (seg == 0) out[(size_t)(m0 + m) * T_ + t] = sum + b3[t];
    }
}

extern "C" void kernel_launch(void* const* d_in, const int* in_sizes, int n_in,
                              void* d_out, int out_size, void* d_ws, size_t ws_size,
                              hipStream_t stream) {
    const float* x  = (const float*)d_in[0];
    const float* W1 = (const float*)d_in[1];
    const float* b1 = (const float*)d_in[2];
    const float* W2 = (const float*)d_in[3];
    const float* b2 = (const float*)d_in[4];
    const float* W3 = (const float*)d_in[5];
    const float* b3 = (const float*)d_in[6];
    float* out = (float*)d_out;

    const size_t nx  = (size_t)B_ * IN_;        // 3,145,728
    const size_t nw1 = (size_t)T_ * IN_ * H_;   // 25,165,824
    const size_t nw2 = (size_t)T_ * H_ * H_;    // 8,388,608

    bf16_t* xt  = (bf16_t*)d_ws;
    bf16_t* w1t = xt + nx;
    bf16_t* w2t = w1t + nw1;

    tile_x_kernel<<<dim3((unsigned)(nx / 8 / 256)), 256, 0, stream>>>(x, xt, (long long)(nx / 8));
    tile_w2<<<dim3(T_ * KC1), 256, 0, stream>>>(W1, w1t, IN_, KC1);
    tile_w2<<<dim3(T_ * KC2), 256, 0, stream>>>(W2, w2t, H_, KC2);

    mtmlp_fused3<<<dim3(2048), 512, 0, stream>>>(xt, w1t, b1, w2t, b2, W3, b3, out);
}